// Round 2
// baseline (144.922 us; speedup 1.0000x reference)
//
#include <hip/hip_runtime.h>

#define B_ 16
#define C_ 306
#define T_ 4000
#define M_ 128

typedef short bf16x8 __attribute__((ext_vector_type(8)));
typedef float f32x4 __attribute__((ext_vector_type(4)));

// W fragment array: [b][chunk(40)][m(128)][hl(2)][slot(8)] u16
// chunk = c>>3 (c = chunk*8 + slot); per-b size = 40*128*16 = 81920 u16
#define WF_PER_B 81920

// ---------- Kernel A: gate MLP -> W in MFMA-fragment order + scale[B,M] ------
__global__ __launch_bounds__(320)
void gate_kernel(const float* __restrict__ positions,   // [B,C,2]
                 const float* __restrict__ target,      // [M,2]
                 const float* __restrict__ w1,          // [3,32]
                 const float* __restrict__ b1,          // [32]
                 const float* __restrict__ w2,          // [32]
                 const float* __restrict__ b2,          // [1]
                 unsigned short* __restrict__ wf,       // fragment-order W
                 float* __restrict__ scale) {           // [B,M]
    const int b  = blockIdx.x >> 5;     // 512 blocks = B * 32
    const int mg = blockIdx.x & 31;     // group of 4 m
    const int tid = threadIdx.x;        // 0..319  (= c)

    __shared__ float s_w1[96], s_b1[32], s_w2[32];
    __shared__ float s_b2;
    __shared__ float s_tgt[8];
    __shared__ float s_part[4][5];
    __shared__ unsigned short s_frag[40 * 72];

    if (tid < 96) s_w1[tid] = w1[tid];
    if (tid < 32) { s_b1[tid] = b1[tid]; s_w2[tid] = w2[tid]; }
    if (tid == 256) s_b2 = b2[0];
    if (tid >= 312) s_tgt[tid - 312] = target[mg * 8 + (tid - 312)];
    __syncthreads();

    float px = 0.0f, py = 0.0f;
    if (tid < C_) {
        px = positions[(b * C_ + tid) * 2 + 0];
        py = positions[(b * C_ + tid) * 2 + 1];
    }

    float wv_[4];
#pragma unroll
    for (int mi = 0; mi < 4; ++mi) {
        float w = 0.0f;
        if (tid < C_) {
            const float dx = px - s_tgt[mi * 2 + 0];
            const float dy = py - s_tgt[mi * 2 + 1];
            const float d2 = dx * dx + dy * dy;
            const float s2 = __expf(-d2 * 3.125f);
            const float q  = s2 * s2;
            const float s1 = q * q;
            const float r  = s1 * s1;
            const float s0 = r * r;
            float acc = s_b2;
#pragma unroll
            for (int j = 0; j < 32; ++j) {
                float h = fmaf(s0, s_w1[j],
                          fmaf(s1, s_w1[32 + j],
                          fmaf(s2, s_w1[64 + j], s_b1[j])));
                acc = fmaf(fmaxf(h, 0.0f), s_w2[j], acc);
            }
            w = acc;
        }
        wv_[mi] = w;
    }

#pragma unroll
    for (int mi = 0; mi < 4; ++mi) {
        float s = wv_[mi];
#pragma unroll
        for (int off = 32; off > 0; off >>= 1) s += __shfl_down(s, off, 64);
        if ((tid & 63) == 0) s_part[mi][tid >> 6] = s;
    }

    const int chunk = tid >> 3;   // 0..39
    const int slot  = tid & 7;
#pragma unroll
    for (int mi = 0; mi < 4; ++mi) {
        const float w = wv_[mi];
        const unsigned int u = __float_as_uint(w);
        const unsigned short h = (unsigned short)(u >> 16);
        const float lof = w - __uint_as_float(u & 0xffff0000u);
        const unsigned short l = (unsigned short)(__float_as_uint(lof) >> 16);
        s_frag[chunk * 72 + mi * 16 + 0 + slot] = h;
        s_frag[chunk * 72 + mi * 16 + 8 + slot] = l;
    }
    __syncthreads();

    if (tid < 4) {
        float tot = s_part[tid][0] + s_part[tid][1] + s_part[tid][2]
                  + s_part[tid][3] + s_part[tid][4];
        scale[b * M_ + mg * 4 + tid] = 1.0f / (tot + 1e-8f);
    }

    {
        const int ch = tid >> 3;       // 0..39
        const int g  = tid & 7;        // (mi = g>>1, hl = g&1)
        const uint4 v = *(const uint4*)(s_frag + ch * 72 + g * 8);
        unsigned short* dst = wf + (size_t)b * WF_PER_B
                            + (size_t)ch * 2048 + mg * 64 + g * 8;
        *(uint4*)dst = v;
    }
}

// ---------- Kernel B: MFMA GEMM  out[b][m][t] = scale[b][m] * sum_c w*x ------
// 256 threads, tile 128m x 128t, 4 waves of 64x64, BK=32, 10 steps fully
// unrolled. Double-buffered X LDS, ONE raw s_barrier per step with an
// lgkmcnt(0)-only drain (NOT __syncthreads: that would emit vmcnt(0) and
// drain the global-load pipeline every step). x is prefetched TWO steps
// ahead (latency budget ~1.5 steps > HBM miss latency); W is refilled from
// L2 right after the MFMA phase (no shadow registers needed).
// Each raw s_barrier is bracketed by compiler memory fences (empty asm with
// "memory" clobber) so LDS reads/writes cannot be moved across it by the
// scheduler (llvm.amdgcn.s.barrier is not an IR-level memory fence).
#define RUNSTRIDE 648   // 32 TQ * 20 words + 8 skew (mod 32 = 8)

__global__ __launch_bounds__(256, 2)
void merge_gemm(const float* __restrict__ x,            // [B,C,T]
                const unsigned short* __restrict__ wf,  // fragment-order W
                const float* __restrict__ scale,        // [B,M]
                float* __restrict__ out) {              // [B,M,T]
    const int t0 = blockIdx.x * 128;
    const int b  = blockIdx.y;
    const int tid  = threadIdx.x;     // 0..255
    const int lane = tid & 63;
    const int wv   = tid >> 6;        // 0..3
    const int tquad = lane >> 4;      // 0..3
    const int tsub  = lane & 15;      // 0..15

    __shared__ __align__(16) unsigned int sXh[2][4 * RUNSTRIDE];
    __shared__ __align__(16) unsigned int sXl[2][4 * RUNSTRIDE];
    __shared__ __align__(16) float sScale[M_];

    if (tid < M_) sScale[tid] = scale[b * M_ + tid];

    const float* xb = x + (size_t)b * C_ * T_;
    const unsigned short* wfB = wf + (size_t)b * WF_PER_B;

    f32x4 acc[4][4];
#pragma unroll
    for (int i = 0; i < 4; ++i)
#pragma unroll
        for (int j = 0; j < 4; ++j) acc[i][j] = (f32x4){0.f, 0.f, 0.f, 0.f};

    const int mw = (wv & 1) * 64;    // wave m-origin
    const int tw = (wv >> 1) * 64;   // wave t-origin

    // staging: thread owns c-pairs {cpB, cpB+8} at t-quad TQ
    const int cpB = tid >> 5;        // 0..7
    const int TQ  = tid & 31;        // 0..31
    const float* xcol = xb + min(t0 + TQ * 4, T_ - 4);

    // ---- helpers as lambdas (inlined) ----
    auto loadX = [&](int k, float4* xv) {
#pragma unroll
        for (int sub = 0; sub < 2; ++sub) {
            const int cp = cpB + 8 * sub;
            const int c  = k * 32 + 2 * cp;
            xv[sub * 2 + 0] = *(const float4*)(xcol + (size_t)min(c,     C_ - 1) * T_);
            xv[sub * 2 + 1] = *(const float4*)(xcol + (size_t)min(c + 1, C_ - 1) * T_);
        }
    };
    auto loadW = [&](int k, bf16x8* ah_, bf16x8* al_) {
#pragma unroll
        for (int mi = 0; mi < 4; ++mi) {
            const size_t aoff = ((size_t)(k * 4 + tquad) * 128
                               + (mw + mi * 16 + tsub)) * 16;
            ah_[mi] = *(const bf16x8*)(wfB + aoff);
            al_[mi] = *(const bf16x8*)(wfB + aoff + 8);
        }
    };
    auto packX = [&](const float4* xv, unsigned int* Dh, unsigned int* Dl) {
#pragma unroll
        for (int sub = 0; sub < 2; ++sub) {
            const int cp  = cpB + 8 * sub;
            const int run = cp >> 2;
            const int pw  = cp & 3;
            const float* fa = (const float*)&xv[sub * 2 + 0];
            const float* fb = (const float*)&xv[sub * 2 + 1];
            const int base = run * RUNSTRIDE + TQ * 20 + pw;
#pragma unroll
            for (int tt = 0; tt < 4; ++tt) {
                const unsigned int ua = __float_as_uint(fa[tt]);
                const unsigned int ub = __float_as_uint(fb[tt]);
                const float la = fa[tt] - __uint_as_float(ua & 0xffff0000u);
                const float lb = fb[tt] - __uint_as_float(ub & 0xffff0000u);
                // hi halves of (ua,ub) packed:  (ua>>16) | (ub & 0xffff0000)
                Dh[base + tt * 4] = __builtin_amdgcn_perm(ub, ua, 0x07060302u);
                Dl[base + tt * 4] = __builtin_amdgcn_perm(__float_as_uint(lb),
                                                          __float_as_uint(la),
                                                          0x07060302u);
            }
        }
    };

    // ---- prologue: stage step 0, issue step-1 x loads (2-deep pipe) ----
    bf16x8 ah[4], al[4];
    float4 xv0[4], xv1[4];
    loadX(0, xv0);
    loadX(1, xv1);          // stays in flight across the barrier
    loadW(0, ah, al);
    packX(xv0, &sXh[0][0], &sXl[0][0]);
    asm volatile("s_waitcnt lgkmcnt(0)" ::: "memory");
    __builtin_amdgcn_s_barrier();
    asm volatile("" ::: "memory");   // pin: no LDS reads hoist above barrier

    // step k: consumes buf[k&1] + W(k); xnext holds x(k+1) (packed at end),
    // xfetch receives x(k+2) (packed at end of step k+1).
    auto step = [&](const int k, float4 (&xnext)[4], float4 (&xfetch)[4]) {
        if (k < 8) loadX(k + 2, xfetch);   // 2 steps ahead, reg-only

        // B fragments from LDS buf[k&1]
        const unsigned int* Sh = &sXh[k & 1][0];
        const unsigned int* Sl = &sXl[k & 1][0];
        bf16x8 bh[4], bl[4];
#pragma unroll
        for (int i = 0; i < 4; ++i) {
            const int t = tw + i * 16 + tsub;
            const int a = tquad * RUNSTRIDE + (t >> 2) * 20 + (t & 3) * 4;
            bh[i] = *(const bf16x8*)(Sh + a);
            bl[i] = *(const bf16x8*)(Sl + a);
        }

        // 48 MFMAs, product-major: 16 independent MFMAs between dependent
        // accumulator reuses; per-acc add order (hh, hl, lh) unchanged ->
        // bitwise-identical result.
#pragma unroll
        for (int mi = 0; mi < 4; ++mi)
#pragma unroll
            for (int ti = 0; ti < 4; ++ti)
                acc[mi][ti] = __builtin_amdgcn_mfma_f32_16x16x32_bf16(
                    ah[mi], bh[ti], acc[mi][ti], 0, 0, 0);
#pragma unroll
        for (int mi = 0; mi < 4; ++mi)
#pragma unroll
            for (int ti = 0; ti < 4; ++ti)
                acc[mi][ti] = __builtin_amdgcn_mfma_f32_16x16x32_bf16(
                    ah[mi], bl[ti], acc[mi][ti], 0, 0, 0);
#pragma unroll
        for (int mi = 0; mi < 4; ++mi)
#pragma unroll
            for (int ti = 0; ti < 4; ++ti)
                acc[mi][ti] = __builtin_amdgcn_mfma_f32_16x16x32_bf16(
                    al[mi], bh[ti], acc[mi][ti], 0, 0, 0);

        if (k < 9) {
            // refill W(k+1) in place (L2-resident; pack VALU + barrier +
            // ds_read window covers the ~200cy L2 hit)
            loadW(k + 1, ah, al);
            // pack x(k+1) (loaded at step k-1 -> ~1.5 steps of latency
            // hidden) into the other buffer
            packX(xnext, &sXh[(k + 1) & 1][0], &sXl[(k + 1) & 1][0]);
            // drain ONLY lds ops; x(k+2)/W(k+1) global loads stay in
            // flight across the barrier (T4 counted-wait pattern)
            asm volatile("s_waitcnt lgkmcnt(0)" ::: "memory");
            __builtin_amdgcn_s_barrier();
            asm volatile("" ::: "memory");  // pin reads below the barrier
        }
    };

#pragma unroll
    for (int kk = 0; kk < 5; ++kk) {
        step(2 * kk,     xv1, xv0);
        step(2 * kk + 1, xv0, xv1);
    }

    // ---- epilogue: fold scale, store (C/D: col = lane&15, row = quad*4+reg)
#pragma unroll
    for (int mi = 0; mi < 4; ++mi) {
        const int mbase = mw + mi * 16 + tquad * 4;
        const float4 sc = *(const float4*)(sScale + mbase);
        float* op = out + ((size_t)b * M_ + mbase) * T_;
#pragma unroll
        for (int ti = 0; ti < 4; ++ti) {
            const int tg = t0 + tw + ti * 16 + tsub;
            if (tg < T_) {
                op[(size_t)0 * T_ + tg] = acc[mi][ti][0] * sc.x;
                op[(size_t)1 * T_ + tg] = acc[mi][ti][1] * sc.y;
                op[(size_t)2 * T_ + tg] = acc[mi][ti][2] * sc.z;
                op[(size_t)3 * T_ + tg] = acc[mi][ti][3] * sc.w;
            }
        }
    }
}

extern "C" void kernel_launch(void* const* d_in, const int* in_sizes, int n_in,
                              void* d_out, int out_size, void* d_ws, size_t ws_size,
                              hipStream_t stream) {
    const float* x         = (const float*)d_in[0];
    const float* positions = (const float*)d_in[1];
    const float* target    = (const float*)d_in[2];
    const float* w1        = (const float*)d_in[3];
    const float* b1        = (const float*)d_in[4];
    const float* b2_dummy  = (const float*)d_in[6];
    const float* w2        = (const float*)d_in[5];
    const float* b2        = b2_dummy;
    float* out = (float*)d_out;

    float* scale = (float*)d_ws;                             // B*M floats
    unsigned short* wf = (unsigned short*)(scale + B_ * M_); // 16*81920 u16

    gate_kernel<<<B_ * 32, 320, 0, stream>>>(positions, target, w1, b1, w2, b2,
                                             wf, scale);

    dim3 grid((T_ + 127) / 128, B_);
    merge_gemm<<<grid, 256, 0, stream>>>(x, wf, scale, out);
}